// Round 1
// baseline (11532.885 us; speedup 1.0000x reference)
//
#include <hip/hip_runtime.h>

// Problem constants (fixed by setup_inputs)
#define B_   8
#define NQ_  200
#define S_   4096
#define E_   2048
#define H_   8
#define CH_  256     // E/H
#define NN_  100     // n (first-n queries -> gumbel branch)

// ---------------------------------------------------------------------------
// Threefry-2x32, JAX partitionable scheme: key = (0, 42); per flat index i:
// x = (hi32(i)=0, lo32(i)=i); bits = out0 ^ out1.
// ---------------------------------------------------------------------------
__device__ __forceinline__ unsigned rotl32(unsigned x, int d) {
    return (x << d) | (x >> (32 - d));
}

__device__ __forceinline__ unsigned threefry_bits(unsigned x0, unsigned x1) {
    const unsigned ks0 = 0u;
    const unsigned ks1 = 42u;
    const unsigned ks2 = 0x1BD11BDAu ^ 0u ^ 42u;
    x0 += ks0; x1 += ks1;
#define TFR(d) { x0 += x1; x1 = rotl32(x1, d); x1 ^= x0; }
    TFR(13) TFR(15) TFR(26) TFR(6)
    x0 += ks1; x1 += ks2 + 1u;
    TFR(17) TFR(29) TFR(16) TFR(24)
    x0 += ks2; x1 += ks0 + 2u;
    TFR(13) TFR(15) TFR(26) TFR(6)
    x0 += ks0; x1 += ks1 + 3u;
    TFR(17) TFR(29) TFR(16) TFR(24)
    x0 += ks1; x1 += ks2 + 4u;
    TFR(13) TFR(15) TFR(26) TFR(6)
    x0 += ks2; x1 += ks0 + 5u;
#undef TFR
    return x0 ^ x1;   // partitionable fold for 32-bit draws
}

// Exact replication of jax.random.uniform f32 bit manipulation, then Gumbel in f64.
__device__ __forceinline__ double gumbel_from_index(unsigned i) {
    unsigned bits = threefry_bits(0u, i);
    float f = __uint_as_float((bits >> 9) | 0x3F800000u) - 1.0f;   // [0,1)
    const float minv = 1e-6f;
    const float maxv = (float)(1.0 - 1e-6);
    float span = __fsub_rn(maxv, minv);
    float u = __fadd_rn(__fmul_rn(f, span), minv);   // mul then add, unfused like XLA
    u = fmaxf(minv, u);
    double lg = log((double)u);
    return -log(-lg);
}

// ---------------------------------------------------------------------------
// Generic tiled f32 GEMM: C = A * op(B) (+bias), 128x128 tile, 8x8 microtile.
// TB=false: B is KxN (ldb);  TB=true: B is NxK (ldb), i.e. C = A * B^T.
// Batched over blockIdx.z with z = zo*8 + zi offsets (pass 0 strides if unused).
// ---------------------------------------------------------------------------
template <bool TB, bool BIAS>
__global__ __launch_bounds__(256)
void gemm_f32(const float* __restrict__ A, const float* __restrict__ Bm,
              const float* __restrict__ bias, float* __restrict__ C,
              int M, int N, int K, int lda, int ldb, int ldc,
              long saO, long saI, long sbO, long sbI, long scO, long scI)
{
    const int z  = blockIdx.z;
    const int zo = z >> 3, zi = z & 7;
    A  += (long)zo * saO + (long)zi * saI;
    Bm += (long)zo * sbO + (long)zi * sbI;
    C  += (long)zo * scO + (long)zi * scI;

    const int tid = threadIdx.x;
    const int n0  = blockIdx.x * 128;
    const int m0  = blockIdx.y * 128;

    __shared__ float As[16][132];
    __shared__ float Bs[16][132];

    float acc[8][8] = {};

    const int tx = tid & 15, ty = tid >> 4;

    for (int k0 = 0; k0 < K; k0 += 16) {
        // ---- stage A tile (transposed): As[kk][m]
        {
            const int kk = (tid & 3) * 4;
#pragma unroll
            for (int p = 0; p < 2; ++p) {
                const int mi = (tid >> 2) + p * 64;
                const int m  = m0 + mi;
                float4 v = make_float4(0.f, 0.f, 0.f, 0.f);
                if (m < M) v = *(const float4*)(A + (long)m * lda + k0 + kk);
                As[kk + 0][mi] = v.x; As[kk + 1][mi] = v.y;
                As[kk + 2][mi] = v.z; As[kk + 3][mi] = v.w;
            }
        }
        // ---- stage B tile: Bs[kk][n]
        if (TB) {
            const int kk = (tid & 3) * 4;
#pragma unroll
            for (int p = 0; p < 2; ++p) {
                const int ni = (tid >> 2) + p * 64;
                const int nn = n0 + ni;
                float4 v = make_float4(0.f, 0.f, 0.f, 0.f);
                if (nn < N) v = *(const float4*)(Bm + (long)nn * ldb + k0 + kk);
                Bs[kk + 0][ni] = v.x; Bs[kk + 1][ni] = v.y;
                Bs[kk + 2][ni] = v.z; Bs[kk + 3][ni] = v.w;
            }
        } else {
#pragma unroll
            for (int p = 0; p < 2; ++p) {
                const int kk = (tid >> 5) + p * 8;
                const int ni = (tid & 31) * 4;
                float4 v = *(const float4*)(Bm + (long)(k0 + kk) * ldb + n0 + ni);
                *(float4*)&Bs[kk][ni] = v;
            }
        }
        __syncthreads();

#pragma unroll
        for (int kk = 0; kk < 16; ++kk) {
            float a[8], b[8];
            *(float4*)&a[0] = *(const float4*)&As[kk][ty * 8];
            *(float4*)&a[4] = *(const float4*)&As[kk][ty * 8 + 4];
            *(float4*)&b[0] = *(const float4*)&Bs[kk][tx * 8];
            *(float4*)&b[4] = *(const float4*)&Bs[kk][tx * 8 + 4];
#pragma unroll
            for (int i = 0; i < 8; ++i)
#pragma unroll
                for (int j = 0; j < 8; ++j)
                    acc[i][j] += a[i] * b[j];
        }
        __syncthreads();
    }

    // ---- epilogue
    float bj[8];
    if (BIAS) {
#pragma unroll
        for (int j = 0; j < 8; ++j) bj[j] = bias[n0 + tx * 8 + j];
    }
#pragma unroll
    for (int i = 0; i < 8; ++i) {
        const int m = m0 + ty * 8 + i;
        if (m >= M) break;
        float4 o0, o1;
        o0.x = acc[i][0]; o0.y = acc[i][1]; o0.z = acc[i][2]; o0.w = acc[i][3];
        o1.x = acc[i][4]; o1.y = acc[i][5]; o1.z = acc[i][6]; o1.w = acc[i][7];
        if (BIAS) {
            o0.x += bj[0]; o0.y += bj[1]; o0.z += bj[2]; o0.w += bj[3];
            o1.x += bj[4]; o1.y += bj[5]; o1.z += bj[6]; o1.w += bj[7];
        }
        float* cp = C + (long)m * ldc + n0 + tx * 8;
        *(float4*)cp       = o0;
        *(float4*)(cp + 4) = o1;
    }
}

// ---------------------------------------------------------------------------
// Row 1/||row|| (double) over E_ elements. Row r -> batch b = r/perBatch,
// local i = r%perBatch, row ptr = src + b*batchStride + i*E_.
// ---------------------------------------------------------------------------
__global__ __launch_bounds__(256)
void row_invnorm(const float* __restrict__ src, double* __restrict__ out,
                 int perBatch, long batchStride)
{
    const int r = blockIdx.x;
    const int b = r / perBatch, i = r % perBatch;
    const float* row = src + (long)b * batchStride + (long)i * E_;
    double s = 0.0;
    for (int c = threadIdx.x; c < E_; c += 256) {
        float v = row[c];
        s += (double)v * (double)v;
    }
    for (int off = 32; off; off >>= 1) s += __shfl_down(s, off, 64);
    __shared__ double wred[4];
    if ((threadIdx.x & 63) == 0) wred[threadIdx.x >> 6] = s;
    __syncthreads();
    if (threadIdx.x == 0)
        out[r] = 1.0 / sqrt(wred[0] + wred[1] + wred[2] + wred[3]);
}

// ---------------------------------------------------------------------------
// Gumbel branch: for each (b,h,k) compute argmax_q [ (cos(q1h_q,k1h_k)+g)/tau ]
// and scatter-add vh[k] into outcat row idx (atomic f32).
// Block: (k-tile of 32) x h x b; 256 threads = 32 k x 8 lanes.
// ---------------------------------------------------------------------------
__global__ __launch_bounds__(256)
void gumbel_argmax_scatter(const float* __restrict__ qp, const float* __restrict__ kp,
                           const float* __restrict__ vp,
                           const double* __restrict__ invqn, const double* __restrict__ invkn,
                           const float* __restrict__ taup,
                           float* __restrict__ outcat)
{
    const int kt  = blockIdx.x;            // 0..127
    const int h   = blockIdx.y;
    const int b   = blockIdx.z;
    const int tid = threadIdx.x;
    const int k0  = kt * 32;

    __shared__ double gl[NN_ * 32];        // 25.6 KB
    __shared__ int    idxs[32];

    const double tau = (double)taup[0];

    // phase 0: gumbel noise for this (b,h,ktile); flat index = ((b*H+h)*NN+q)*S + k
    for (int e = tid; e < NN_ * 32; e += 256) {
        const int q = e >> 5, kl = e & 31;
        const unsigned i = (unsigned)(((b * H_ + h) * NN_ + q) * S_ + (k0 + kl));
        gl[e] = gumbel_from_index(i);
    }
    __syncthreads();

    const int kl = tid >> 3, l8 = tid & 7;

    // preload this thread's K segment (32 floats of the 256-dim head row)
    float ks[32];
    const float* krow = kp + ((long)b * S_ + (k0 + kl)) * E_ + h * CH_ + l8 * 32;
#pragma unroll
    for (int j4 = 0; j4 < 8; ++j4)
        *(float4*)&ks[j4 * 4] = *(const float4*)(krow + j4 * 4);

    const double ikn = invkn[b * S_ + k0 + kl];
    double best = -1e300;
    int bi = 0;

    for (int q = 0; q < NN_; ++q) {
        const float* qrow = qp + ((long)b * NQ_ + q) * E_ + h * CH_ + l8 * 32;
        float s = 0.f;
#pragma unroll
        for (int j4 = 0; j4 < 8; ++j4) {
            float4 v = *(const float4*)(qrow + j4 * 4);
            s += ks[j4 * 4 + 0] * v.x + ks[j4 * 4 + 1] * v.y +
                 ks[j4 * 4 + 2] * v.z + ks[j4 * 4 + 3] * v.w;
        }
        s += __shfl_xor(s, 1, 64);
        s += __shfl_xor(s, 2, 64);
        s += __shfl_xor(s, 4, 64);
        if (l8 == 0) {
            double zv = ((double)s * invqn[b * NN_ + q] * ikn + gl[q * 32 + kl]) / tau;
            if (zv > best) { best = zv; bi = q; }
        }
    }
    if (l8 == 0) idxs[kl] = bi;
    __syncthreads();

    // scatter: out1[idx[k]] += vh[k]
    for (int kk = 0; kk < 32; ++kk) {
        const int row = idxs[kk];
        const float v = vp[((long)b * S_ + (k0 + kk)) * E_ + h * CH_ + tid];
        atomicAdd(outcat + ((long)b * NQ_ + row) * E_ + h * CH_ + tid, v);
    }
}

// ---------------------------------------------------------------------------
// Row softmax with 1/16 scale folded in: p = softmax(s/16) over S_ columns.
// One block per row, row staged in LDS.
// ---------------------------------------------------------------------------
__global__ __launch_bounds__(256)
void softmax_rows(float* __restrict__ S2)
{
    const long r = blockIdx.x;
    float* row = S2 + r * (long)S_;
    __shared__ float buf[S_];
    __shared__ float wred[4];
    __shared__ float wsum[4];
    const int tid = threadIdx.x;

    float mx = -1e30f;
    for (int c = tid; c < S_; c += 256) {
        float v = row[c];
        buf[c] = v;
        mx = fmaxf(mx, v);
    }
    for (int off = 32; off; off >>= 1) mx = fmaxf(mx, __shfl_xor(mx, off, 64));
    if ((tid & 63) == 0) wred[tid >> 6] = mx;
    __syncthreads();
    mx = fmaxf(fmaxf(wred[0], wred[1]), fmaxf(wred[2], wred[3]));

    float sum = 0.f;
    for (int c = tid; c < S_; c += 256) {
        float p = __expf((buf[c] - mx) * 0.0625f);
        buf[c] = p;
        sum += p;
    }
    for (int off = 32; off; off >>= 1) sum += __shfl_xor(sum, off, 64);
    if ((tid & 63) == 0) wsum[tid >> 6] = sum;
    __syncthreads();
    sum = wsum[0] + wsum[1] + wsum[2] + wsum[3];
    const float inv = 1.0f / sum;
    for (int c = tid; c < S_; c += 256) row[c] = buf[c] * inv;
}

// ---------------------------------------------------------------------------
// Host-side orchestration.
// ---------------------------------------------------------------------------
extern "C" void kernel_launch(void* const* d_in, const int* in_sizes, int n_in,
                              void* d_out, int out_size, void* d_ws, size_t ws_size,
                              hipStream_t stream)
{
    const float* q   = (const float*)d_in[0];
    const float* k   = (const float*)d_in[1];
    const float* v   = (const float*)d_in[2];
    const float* wq  = (const float*)d_in[3];
    const float* bq  = (const float*)d_in[4];
    const float* wk  = (const float*)d_in[5];
    const float* bk  = (const float*)d_in[6];
    const float* wv  = (const float*)d_in[7];
    const float* bv  = (const float*)d_in[8];
    const float* wo  = (const float*)d_in[9];
    const float* bo  = (const float*)d_in[10];
    const float* tau = (const float*)d_in[11];
    // d_in[12] = n (assumed 100, per setup_inputs)

    char* ws = (char*)d_ws;
    float*  qp     = (float*)(ws + 0L);           // 1600x2048        (13,107,200 B)
    float*  kp     = (float*)(ws + 13107200L);    // 32768x2048       (268,435,456 B)
    float*  vp     = (float*)(ws + 281542656L);   // 32768x2048       (268,435,456 B)
    float*  outcat = (float*)(ws + 549978112L);   // 1600x2048        (13,107,200 B)
    float*  S2     = (float*)(ws + 563085312L);   // 64x100x4096      (104,857,600 B)
    double* iqn    = (double*)(ws + 667942912L);  // 8x100 doubles
    double* ikn    = (double*)(ws + 667949312L);  // 8x4096 doubles

    const dim3 blk(256);

    // 1) projections (f32 accuracy needed for the argmax branch)
    gemm_f32<false, true><<<dim3(16, 13, 1), blk, 0, stream>>>(
        q, wq, bq, qp, 1600, 2048, 2048, 2048, 2048, 2048, 0, 0, 0, 0, 0, 0);
    gemm_f32<false, true><<<dim3(16, 256, 1), blk, 0, stream>>>(
        k, wk, bk, kp, 32768, 2048, 2048, 2048, 2048, 2048, 0, 0, 0, 0, 0, 0);
    gemm_f32<false, true><<<dim3(16, 256, 1), blk, 0, stream>>>(
        v, wv, bv, vp, 32768, 2048, 2048, 2048, 2048, 2048, 0, 0, 0, 0, 0, 0);

    // 2) row norms (q1 rows 0..99 per batch; all kp rows)
    row_invnorm<<<dim3(800), blk, 0, stream>>>(qp, iqn, NN_, (long)NQ_ * E_);
    row_invnorm<<<dim3(32768), blk, 0, stream>>>(kp, ikn, S_, (long)S_ * E_);

    // 3) zero out1/out2 concat buffer (out1 is accumulated atomically)
    hipMemsetAsync(outcat, 0, 13107200, stream);

    // 4) gumbel argmax + scatter (out1 rows 0..99)
    gumbel_argmax_scatter<<<dim3(128, 8, 8), blk, 0, stream>>>(
        qp, kp, vp, iqn, ikn, tau, outcat);

    // 5) attn2 scores: S2[b,h] (100x4096) = q2h (100x256) * kh^T (4096x256)^T
    gemm_f32<true, false><<<dim3(32, 1, 64), blk, 0, stream>>>(
        qp + (long)NN_ * E_, kp, nullptr, S2,
        100, 4096, 256, 2048, 2048, 4096,
        (long)NQ_ * E_, (long)CH_,            // A: b stride, h stride
        (long)S_ * E_, (long)CH_,             // B: b stride, h stride
        (long)H_ * NN_ * S_, (long)NN_ * S_); // C: b stride, h stride

    // 6) softmax over k (scale 1/16 folded in)
    softmax_rows<<<dim3(6400), blk, 0, stream>>>(S2);

    // 7) out2 = P * vh  -> outcat rows 100..199
    gemm_f32<false, false><<<dim3(2, 1, 64), blk, 0, stream>>>(
        S2, vp, nullptr, outcat + (long)NN_ * E_,
        100, 256, 4096, 4096, 2048, 2048,
        (long)H_ * NN_ * S_, (long)NN_ * S_,  // A: b stride, h stride
        (long)S_ * E_, (long)CH_,             // B: b stride, h stride
        (long)NQ_ * E_, (long)CH_);           // C: b stride, h stride

    // 8) final projection
    gemm_f32<false, true><<<dim3(16, 13, 1), blk, 0, stream>>>(
        outcat, wo, bo, (float*)d_out, 1600, 2048, 2048, 2048, 2048, 2048,
        0, 0, 0, 0, 0, 0);
}

// Round 3
// 8547.607 us; speedup vs baseline: 1.3493x; 1.3493x over previous
//
#include <hip/hip_runtime.h>

// Problem constants (fixed by setup_inputs)
#define B_   8
#define NQ_  200
#define S_   4096
#define E_   2048
#define H_   8
#define CH_  256     // E/H
#define NN_  100     // n (first-n queries -> gumbel branch)

typedef short v8s  __attribute__((ext_vector_type(8)));
typedef float v4f  __attribute__((ext_vector_type(4)));

// ---------------------------------------------------------------------------
// Threefry-2x32, JAX partitionable scheme: key = (0, 42); per flat index i:
// x = (hi32(i)=0, lo32(i)=i); bits = out0 ^ out1.
// ---------------------------------------------------------------------------
__device__ __forceinline__ unsigned rotl32(unsigned x, int d) {
    return (x << d) | (x >> (32 - d));
}

__device__ __forceinline__ unsigned threefry_bits(unsigned x0, unsigned x1) {
    const unsigned ks0 = 0u;
    const unsigned ks1 = 42u;
    const unsigned ks2 = 0x1BD11BDAu ^ 0u ^ 42u;
    x0 += ks0; x1 += ks1;
#define TFR(d) { x0 += x1; x1 = rotl32(x1, d); x1 ^= x0; }
    TFR(13) TFR(15) TFR(26) TFR(6)
    x0 += ks1; x1 += ks2 + 1u;
    TFR(17) TFR(29) TFR(16) TFR(24)
    x0 += ks2; x1 += ks0 + 2u;
    TFR(13) TFR(15) TFR(26) TFR(6)
    x0 += ks0; x1 += ks1 + 3u;
    TFR(17) TFR(29) TFR(16) TFR(24)
    x0 += ks1; x1 += ks2 + 4u;
    TFR(13) TFR(15) TFR(26) TFR(6)
    x0 += ks2; x1 += ks0 + 5u;
#undef TFR
    return x0 ^ x1;   // partitionable fold for 32-bit draws
}

// Exact replication of jax.random.uniform f32 bit manipulation, then Gumbel in f64.
__device__ __forceinline__ double gumbel_from_index(unsigned i) {
    unsigned bits = threefry_bits(0u, i);
    float f = __uint_as_float((bits >> 9) | 0x3F800000u) - 1.0f;   // [0,1)
    const float minv = 1e-6f;
    const float maxv = (float)(1.0 - 1e-6);
    float span = __fsub_rn(maxv, minv);
    float u = __fadd_rn(__fmul_rn(f, span), minv);   // mul then add, unfused like XLA
    u = fmaxf(minv, u);
    double lg = log((double)u);
    return -log(-lg);
}

// f32 -> bf16 (RNE)
__device__ __forceinline__ unsigned short f2bf(float f) {
    unsigned u = __float_as_uint(f);
    unsigned r = (u + 0x7FFFu + ((u >> 16) & 1u)) >> 16;
    return (unsigned short)r;
}

// async global->LDS, 16B per lane
#define ASYNC16(g, l)                                                          \
    __builtin_amdgcn_global_load_lds(                                          \
        (const __attribute__((address_space(1))) unsigned*)(g),                \
        (__attribute__((address_space(3))) unsigned*)(l), 16, 0, 0)

// ---------------------------------------------------------------------------
// Generic tiled f32 GEMM: C = A * op(B) (+bias), 128x128 tile, 8x8 microtile.
// Microtile reads at stride-4 (2-way LDS aliasing = free).
// TB=false: B is KxN (ldb);  TB=true: B is NxK (ldb), i.e. C = A * B^T.
// Batched over blockIdx.z with z = zo*8 + zi offsets (pass 0 strides if unused).
// ---------------------------------------------------------------------------
template <bool TB, bool BIAS>
__global__ __launch_bounds__(256)
void gemm_f32(const float* __restrict__ A, const float* __restrict__ Bm,
              const float* __restrict__ bias, float* __restrict__ C,
              int M, int N, int K, int lda, int ldb, int ldc,
              long saO, long saI, long sbO, long sbI, long scO, long scI)
{
    const int z  = blockIdx.z;
    const int zo = z >> 3, zi = z & 7;
    A  += (long)zo * saO + (long)zi * saI;
    Bm += (long)zo * sbO + (long)zi * sbI;
    C  += (long)zo * scO + (long)zi * scI;

    const int tid = threadIdx.x;
    const int n0  = blockIdx.x * 128;
    const int m0  = blockIdx.y * 128;

    __shared__ float As[16][132];
    __shared__ float Bs[16][132];

    float acc[8][8] = {};

    const int tx = tid & 15, ty = tid >> 4;

    for (int k0 = 0; k0 < K; k0 += 16) {
        // ---- stage A tile (transposed): As[kk][m]
        {
            const int kk = (tid & 3) * 4;
#pragma unroll
            for (int p = 0; p < 2; ++p) {
                const int mi = (tid >> 2) + p * 64;
                const int m  = m0 + mi;
                float4 v = make_float4(0.f, 0.f, 0.f, 0.f);
                if (m < M) v = *(const float4*)(A + (long)m * lda + k0 + kk);
                As[kk + 0][mi] = v.x; As[kk + 1][mi] = v.y;
                As[kk + 2][mi] = v.z; As[kk + 3][mi] = v.w;
            }
        }
        // ---- stage B tile: Bs[kk][n]
        if (TB) {
            const int kk = (tid & 3) * 4;
#pragma unroll
            for (int p = 0; p < 2; ++p) {
                const int ni = (tid >> 2) + p * 64;
                const int nn = n0 + ni;
                float4 v = make_float4(0.f, 0.f, 0.f, 0.f);
                if (nn < N) v = *(const float4*)(Bm + (long)nn * ldb + k0 + kk);
                Bs[kk + 0][ni] = v.x; Bs[kk + 1][ni] = v.y;
                Bs[kk + 2][ni] = v.z; Bs[kk + 3][ni] = v.w;
            }
        } else {
#pragma unroll
            for (int p = 0; p < 2; ++p) {
                const int kk = (tid >> 5) + p * 8;
                const int ni = (tid & 31) * 4;
                float4 v = *(const float4*)(Bm + (long)(k0 + kk) * ldb + n0 + ni);
                *(float4*)&Bs[kk][ni] = v;
            }
        }
        __syncthreads();

#pragma unroll
        for (int kk = 0; kk < 16; ++kk) {
            float a[8], b[8];
            *(float4*)&a[0] = *(const float4*)&As[kk][ty * 4];
            *(float4*)&a[4] = *(const float4*)&As[kk][64 + ty * 4];
            *(float4*)&b[0] = *(const float4*)&Bs[kk][tx * 4];
            *(float4*)&b[4] = *(const float4*)&Bs[kk][64 + tx * 4];
#pragma unroll
            for (int i = 0; i < 8; ++i)
#pragma unroll
                for (int j = 0; j < 8; ++j)
                    acc[i][j] += a[i] * b[j];
        }
        __syncthreads();
    }

    // ---- epilogue (rows: i<4 -> m0+ty*4+i, i>=4 -> m0+64+ty*4+i-4;
    //                cols: j<4 -> n0+tx*4+j, j>=4 -> n0+64+tx*4+j-4)
    float bj[8] = {};
    if (BIAS) {
#pragma unroll
        for (int j = 0; j < 4; ++j) bj[j]     = bias[n0 + tx * 4 + j];
#pragma unroll
        for (int j = 0; j < 4; ++j) bj[4 + j] = bias[n0 + 64 + tx * 4 + j];
    }
#pragma unroll
    for (int i = 0; i < 8; ++i) {
        const int m = m0 + (i < 4 ? ty * 4 + i : 64 + ty * 4 + (i - 4));
        if (m >= M) continue;
        float4 o0, o1;
        o0.x = acc[i][0] + bj[0]; o0.y = acc[i][1] + bj[1];
        o0.z = acc[i][2] + bj[2]; o0.w = acc[i][3] + bj[3];
        o1.x = acc[i][4] + bj[4]; o1.y = acc[i][5] + bj[5];
        o1.z = acc[i][6] + bj[6]; o1.w = acc[i][7] + bj[7];
        float* cp = C + (long)m * ldc + n0;
        *(float4*)(cp + tx * 4)      = o0;
        *(float4*)(cp + 64 + tx * 4) = o1;
    }
}

// ---------------------------------------------------------------------------
// bf16 MFMA GEMM (m97 structure): C(f32, MxN) = A(bf16, MxK) * Bt(bf16, NxK)^T
// 128x128 tile, BK=32, 4 waves, 4x4 16x16x32 MFMA tiles per wave (ONE mfma
// per tile per BK=32 round: the instruction consumes K=32, a-frag k=quad*8+j).
// ---------------------------------------------------------------------------
template <bool BIAS>
__global__ __launch_bounds__(256)
void gemm_bf16_bt(const unsigned short* __restrict__ A,
                  const unsigned short* __restrict__ Bt,
                  const float* __restrict__ bias,
                  float* __restrict__ C,
                  int M, int N, int K)
{
    __shared__ unsigned short Asm[128 * 32];
    __shared__ unsigned short Bsm[128 * 32];

    const int tid  = threadIdx.x;
    const int lane = tid & 63;
    const int wave = tid >> 6;
    const int m0 = blockIdx.y * 128;
    const int n0 = blockIdx.x * 128;

    const int woffm = (wave & 1) * 64;
    const int woffn = (wave >> 1) * 64;
    const int mrow = lane & 15;
    const int quad = lane >> 4;
    const int ko   = quad * 8;          // k-offset of this lane's fragment

    v4f acc[4][4] = {};

    // staging addresses: chunk c (0..511): row = c>>2, k-elt-offset = (c&3)*8
    const long  arow0 = (long)(m0 + (tid >> 2)) * K + (tid & 3) * 8;
    const long  arow1 = (long)(m0 + 64 + (tid >> 2)) * K + (tid & 3) * 8;
    const long  brow0 = (long)(n0 + (tid >> 2)) * K + (tid & 3) * 8;
    const long  brow1 = (long)(n0 + 64 + (tid >> 2)) * K + (tid & 3) * 8;

    for (int k0 = 0; k0 < K; k0 += 32) {
        ASYNC16(A + arow0 + k0,  &Asm[tid * 8]);
        ASYNC16(A + arow1 + k0,  &Asm[(256 + tid) * 8]);
        ASYNC16(Bt + brow0 + k0, &Bsm[tid * 8]);
        ASYNC16(Bt + brow1 + k0, &Bsm[(256 + tid) * 8]);
        __syncthreads();

        v8s a[4], b[4];
#pragma unroll
        for (int i = 0; i < 4; ++i)
            a[i] = *(const v8s*)&Asm[(woffm + i * 16 + mrow) * 32 + ko];
#pragma unroll
        for (int j = 0; j < 4; ++j)
            b[j] = *(const v8s*)&Bsm[(woffn + j * 16 + mrow) * 32 + ko];
#pragma unroll
        for (int i = 0; i < 4; ++i)
#pragma unroll
            for (int j = 0; j < 4; ++j)
                acc[i][j] = __builtin_amdgcn_mfma_f32_16x16x32_bf16(
                    a[i], b[j], acc[i][j], 0, 0, 0);
        __syncthreads();
    }

    // epilogue: D col = lane&15, row = quad*4 + r
    const int col = mrow;
    const int r0  = quad * 4;
#pragma unroll
    for (int j = 0; j < 4; ++j) {
        const int n = n0 + woffn + j * 16 + col;
        const float bv = BIAS ? bias[n] : 0.f;
#pragma unroll
        for (int i = 0; i < 4; ++i) {
            const int mbase = m0 + woffm + i * 16 + r0;
#pragma unroll
            for (int r = 0; r < 4; ++r) {
                const int m = mbase + r;
                if (m < M) C[(long)m * N + n] = acc[i][j][r] + bv;
            }
        }
    }
}

// ---------------------------------------------------------------------------
// Casts
// ---------------------------------------------------------------------------
__global__ __launch_bounds__(256)
void cast_f32_bf16(const float* __restrict__ in, unsigned short* __restrict__ out, long n)
{
    long i = ((long)blockIdx.x * 256 + threadIdx.x) * 8;
    if (i + 8 <= n) {
        float4 v0 = *(const float4*)(in + i);
        float4 v1 = *(const float4*)(in + i + 4);
        ushort4 a, b;
        a.x = f2bf(v0.x); a.y = f2bf(v0.y); a.z = f2bf(v0.z); a.w = f2bf(v0.w);
        b.x = f2bf(v1.x); b.y = f2bf(v1.y); b.z = f2bf(v1.z); b.w = f2bf(v1.w);
        *(ushort4*)(out + i)     = a;
        *(ushort4*)(out + i + 4) = b;
    } else {
        for (; i < n; ++i) out[i] = f2bf(in[i]);
    }
}

// W (Kd x Nd f32, row-major) -> Wt (Nd x Kd bf16, row-major)
__global__ __launch_bounds__(256)
void transpose_cast(const float* __restrict__ W, unsigned short* __restrict__ Wt,
                    int Kd, int Nd)
{
    __shared__ float t[32][33];
    const int nb = blockIdx.x * 32, kb = blockIdx.y * 32;
    const int tx = threadIdx.x & 31, ty = threadIdx.x >> 5;
#pragma unroll
    for (int p = 0; p < 4; ++p)
        t[ty + p * 8][tx] = W[(long)(kb + ty + p * 8) * Nd + nb + tx];
    __syncthreads();
#pragma unroll
    for (int p = 0; p < 4; ++p)
        Wt[(long)(nb + ty + p * 8) * Kd + kb + tx] = f2bf(t[tx][ty + p * 8]);
}

// ---------------------------------------------------------------------------
// Row 1/||row|| (double) over E_ elements.
// ---------------------------------------------------------------------------
__global__ __launch_bounds__(256)
void row_invnorm(const float* __restrict__ src, double* __restrict__ out,
                 int perBatch, long batchStride)
{
    const int r = blockIdx.x;
    const int b = r / perBatch, i = r % perBatch;
    const float* row = src + (long)b * batchStride + (long)i * E_;
    double s = 0.0;
    for (int c = threadIdx.x; c < E_; c += 256) {
        float v = row[c];
        s += (double)v * (double)v;
    }
    for (int off = 32; off; off >>= 1) s += __shfl_down(s, off, 64);
    __shared__ double wred[4];
    if ((threadIdx.x & 63) == 0) wred[threadIdx.x >> 6] = s;
    __syncthreads();
    if (threadIdx.x == 0)
        out[r] = 1.0 / sqrt(wred[0] + wred[1] + wred[2] + wred[3]);
}

// ---------------------------------------------------------------------------
// Gumbel branch: for each (b,h,k) compute argmax_q [ (cos(q1h_q,k1h_k)+g)/tau ]
// and scatter-add vh[k] into outcat row idx (atomic f32).
// ---------------------------------------------------------------------------
__global__ __launch_bounds__(256)
void gumbel_argmax_scatter(const float* __restrict__ qp, const float* __restrict__ kp,
                           const float* __restrict__ vp,
                           const double* __restrict__ invqn, const double* __restrict__ invkn,
                           const float* __restrict__ taup,
                           float* __restrict__ outcat)
{
    const int kt  = blockIdx.x;            // 0..127
    const int h   = blockIdx.y;
    const int b   = blockIdx.z;
    const int tid = threadIdx.x;
    const int k0  = kt * 32;

    __shared__ double gl[NN_ * 32];        // 25.6 KB
    __shared__ int    idxs[32];

    const double tau = (double)taup[0];

    for (int e = tid; e < NN_ * 32; e += 256) {
        const int q = e >> 5, kl = e & 31;
        const unsigned i = (unsigned)(((b * H_ + h) * NN_ + q) * S_ + (k0 + kl));
        gl[e] = gumbel_from_index(i);
    }
    __syncthreads();

    const int kl = tid >> 3, l8 = tid & 7;

    float ks[32];
    const float* krow = kp + ((long)b * S_ + (k0 + kl)) * E_ + h * CH_ + l8 * 32;
#pragma unroll
    for (int j4 = 0; j4 < 8; ++j4)
        *(float4*)&ks[j4 * 4] = *(const float4*)(krow + j4 * 4);

    const double ikn = invkn[b * S_ + k0 + kl];
    double best = -1e300;
    int bi = 0;

    for (int q = 0; q < NN_; ++q) {
        const float* qrow = qp + ((long)b * NQ_ + q) * E_ + h * CH_ + l8 * 32;
        float s = 0.f;
#pragma unroll
        for (int j4 = 0; j4 < 8; ++j4) {
            float4 v = *(const float4*)(qrow + j4 * 4);
            s += ks[j4 * 4 + 0] * v.x + ks[j4 * 4 + 1] * v.y +
                 ks[j4 * 4 + 2] * v.z + ks[j4 * 4 + 3] * v.w;
        }
        s += __shfl_xor(s, 1, 64);
        s += __shfl_xor(s, 2, 64);
        s += __shfl_xor(s, 4, 64);
        if (l8 == 0) {
            double zv = ((double)s * invqn[b * NN_ + q] * ikn + gl[q * 32 + kl]) / tau;
            if (zv > best) { best = zv; bi = q; }
        }
    }
    if (l8 == 0) idxs[kl] = bi;
    __syncthreads();

    for (int kk = 0; kk < 32; ++kk) {
        const int row = idxs[kk];
        const float v = vp[((long)b * S_ + (k0 + kk)) * E_ + h * CH_ + tid];
        atomicAdd(outcat + ((long)b * NQ_ + row) * E_ + h * CH_ + tid, v);
    }
}

// ---------------------------------------------------------------------------
// Row softmax with 1/16 scale folded in.
// ---------------------------------------------------------------------------
__global__ __launch_bounds__(256)
void softmax_rows(float* __restrict__ S2)
{
    const long r = blockIdx.x;
    float* row = S2 + r * (long)S_;
    __shared__ float buf[S_];
    __shared__ float wred[4];
    __shared__ float wsum[4];
    const int tid = threadIdx.x;

    float mx = -1e30f;
    for (int c = tid; c < S_; c += 256) {
        float v = row[c];
        buf[c] = v;
        mx = fmaxf(mx, v);
    }
    for (int off = 32; off; off >>= 1) mx = fmaxf(mx, __shfl_xor(mx, off, 64));
    if ((tid & 63) == 0) wred[tid >> 6] = mx;
    __syncthreads();
    mx = fmaxf(fmaxf(wred[0], wred[1]), fmaxf(wred[2], wred[3]));

    float sum = 0.f;
    for (int c = tid; c < S_; c += 256) {
        float p = __expf((buf[c] - mx) * 0.0625f);
        buf[c] = p;
        sum += p;
    }
    for (int off = 32; off; off >>= 1) sum += __shfl_xor(sum, off, 64);
    if ((tid & 63) == 0) wsum[tid >> 6] = sum;
    __syncthreads();
    sum = wsum[0] + wsum[1] + wsum[2] + wsum[3];
    const float inv = 1.0f / sum;
    for (int c = tid; c < S_; c += 256) row[c] = buf[c] * inv;
}

// ---------------------------------------------------------------------------
// Host-side orchestration.
// Workspace layout (total 668,211,456 B — same footprint as the passing R1):
//   [0            , 13,107,200 )  qp  f32 1600x2048
//   [13,107,200   , 281,542,656)  kp  f32 32768x2048        (written AFTER:)
//     [13,107,200 , 147,324,928)    v_bf16 (phase A only, dead before kp)
//     [147,324,928, 155,713,536)    wT1 = wv^T bf16 (phase A only)
//   [281,542,656  , 549,978,112)  vp  f32 32768x2048
//   [549,978,112  , 563,085,312)  outcat f32 1600x2048
//   [563,085,312  , 667,942,912)  S2  f32 64x100x4096       (reused AFTER:)
//     [563,085,312, 569,901,056)    out_bf16 1664x2048 (after S2 consumed)
//     [569,901,056, 578,289,664)    wT2 = wo^T bf16   (after S2 consumed)
//   [667,942,912  , 667,949,312)  iqn  800 f64
//   [667,949,312  , 668,211,456)  ikn  32768 f64
// ---------------------------------------------------------------------------
extern "C" void kernel_launch(void* const* d_in, const int* in_sizes, int n_in,
                              void* d_out, int out_size, void* d_ws, size_t ws_size,
                              hipStream_t stream)
{
    const float* q   = (const float*)d_in[0];
    const float* k   = (const float*)d_in[1];
    const float* v   = (const float*)d_in[2];
    const float* wq  = (const float*)d_in[3];
    const float* bq  = (const float*)d_in[4];
    const float* wk  = (const float*)d_in[5];
    const float* bk  = (const float*)d_in[6];
    const float* wv  = (const float*)d_in[7];
    const float* bv  = (const float*)d_in[8];
    const float* wo  = (const float*)d_in[9];
    const float* bo  = (const float*)d_in[10];
    const float* tau = (const float*)d_in[11];

    char* ws = (char*)d_ws;
    float*          qp       = (float*)(ws + 0L);
    unsigned short* v_bf16   = (unsigned short*)(ws + 13107200L);
    unsigned short* wT1      = (unsigned short*)(ws + 147324928L);
    float*          kp       = (float*)(ws + 13107200L);
    float*          vp       = (float*)(ws + 281542656L);
    float*          outcat   = (float*)(ws + 549978112L);
    float*          S2       = (float*)(ws + 563085312L);
    unsigned short* out_bf16 = (unsigned short*)(ws + 563085312L);
    unsigned short* wT2      = (unsigned short*)(ws + 569901056L);
    double*         iqn      = (double*)(ws + 667942912L);
    double*         ikn      = (double*)(ws + 667949312L);

    const dim3 blk(256);

    // Phase A: vp via bf16 MFMA (scratch lives inside kp's future region)
    cast_f32_bf16<<<dim3(32768), blk, 0, stream>>>(v, v_bf16, (long)32768 * 2048);
    transpose_cast<<<dim3(64, 64), blk, 0, stream>>>(wv, wT1, 2048, 2048);
    gemm_bf16_bt<true><<<dim3(16, 256), blk, 0, stream>>>(
        v_bf16, wT1, bv, vp, 32768, 2048, 2048);

    // Phase B: qp, kp in f32 (argmax precision). kp overwrites v_bf16/wT1.
    gemm_f32<false, true><<<dim3(16, 13, 1), blk, 0, stream>>>(
        q, wq, bq, qp, 1600, 2048, 2048, 2048, 2048, 2048, 0, 0, 0, 0, 0, 0);
    gemm_f32<false, true><<<dim3(16, 256, 1), blk, 0, stream>>>(
        k, wk, bk, kp, 32768, 2048, 2048, 2048, 2048, 2048, 0, 0, 0, 0, 0, 0);

    // Phase C: row norms + gumbel scatter (out1 rows 0..99 of outcat)
    row_invnorm<<<dim3(800), blk, 0, stream>>>(qp, iqn, NN_, (long)NQ_ * E_);
    row_invnorm<<<dim3(32768), blk, 0, stream>>>(kp, ikn, S_, (long)S_ * E_);
    hipMemsetAsync(outcat, 0, 13107200, stream);
    gumbel_argmax_scatter<<<dim3(128, 8, 8), blk, 0, stream>>>(
        qp, kp, vp, iqn, ikn, tau, outcat);

    // Phase D: attn2 -> outcat rows 100..199
    gemm_f32<true, false><<<dim3(32, 1, 64), blk, 0, stream>>>(
        qp + (long)NN_ * E_, kp, nullptr, S2,
        100, 4096, 256, 2048, 2048, 4096,
        (long)NQ_ * E_, (long)CH_,
        (long)S_ * E_, (long)CH_,
        (long)H_ * NN_ * S_, (long)NN_ * S_);
    softmax_rows<<<dim3(6400), blk, 0, stream>>>(S2);
    gemm_f32<false, false><<<dim3(2, 1, 64), blk, 0, stream>>>(
        S2, vp, nullptr, outcat + (long)NN_ * E_,
        100, 256, 4096, 4096, 2048, 2048,
        (long)H_ * NN_ * S_, (long)NN_ * S_,
        (long)S_ * E_, (long)CH_,
        (long)NQ_ * E_, (long)CH_);

    // Phase E: final projection via bf16 MFMA (S2 region reused for scratch)
    cast_f32_bf16<<<dim3(1600), blk, 0, stream>>>(outcat, out_bf16, (long)1600 * 2048);
    transpose_cast<<<dim3(64, 64), blk, 0, stream>>>(wo, wT2, 2048, 2048);
    gemm_bf16_bt<true><<<dim3(16, 13), blk, 0, stream>>>(
        out_bf16, wT2, bo, (float*)d_out, 1600, 2048, 2048);
}